// Round 1
// 2319.428 us; speedup vs baseline: 1.1882x; 1.1882x over previous
//
#include <hip/hip_runtime.h>
#include <stdint.h>

#define BB 256
#define SS 64
#define TT 20
#define HH 1024
#define EE 100
#define G3 3072
#define G4 4096
#define KE 1152     // 1024 + 128 (E padded to 128)
#define VV 32000

typedef unsigned short ushort_t;
typedef short bf16x8 __attribute__((ext_vector_type(8)));
typedef float f32x4 __attribute__((ext_vector_type(4)));

#define DEV static __device__ __forceinline__

DEV float bf2f(ushort_t h) {
    union { uint32_t u; float f; } c; c.u = ((uint32_t)h) << 16; return c.f;
}
DEV ushort_t f2bf(float x) {
    union { float f; uint32_t u; } c; c.f = x;
    uint32_t r = (c.u + 0x7fffu + ((c.u >> 16) & 1u)) >> 16;
    return (ushort_t)r;
}
DEV float sigm(float x) { return 1.f / (1.f + expf(-x)); }

DEV void storeC(float* p, float v) { *p = v; }
DEV void storeC(ushort_t* p, float v) { *p = f2bf(v); }

#define MFMA16(a, b, c) __builtin_amdgcn_mfma_f32_16x16x32_bf16(a, b, c, 0, 0, 0)

// One barrier per K-chunk: drain LDS ops only; global loads stay in flight
// across the barrier (T4 counted-vmcnt via compiler reg-deps).
#define LGKM_BARRIER()                                         \
    do {                                                       \
        asm volatile("s_waitcnt lgkmcnt(0)" ::: "memory");     \
        __builtin_amdgcn_s_barrier();                          \
    } while (0)

// ---------------------------------------------------------------------------
// prep_w: build bf16 W_enc_big [4096][1152], W_dec_pad [3072][1152] from fp32.
// ---------------------------------------------------------------------------
__global__ void prep_w(const float* __restrict__ W_hh_e, const float* __restrict__ W_ih_e,
                       const float* __restrict__ W_ih_d,
                       ushort_t* __restrict__ W_enc_big, ushort_t* __restrict__ W_dec_pad) {
    int idx = blockIdx.x * 256 + threadIdx.x;  // (G4+G3) * (KE/8)
    int n = idx / 144, kc = (idx - n * 144) * 8;
    ushort_t o[8];
    if (n < G4) {
        if (kc < HH) {
            if (n < G3) {
#pragma unroll
                for (int u = 0; u < 8; ++u) o[u] = f2bf(W_hh_e[(size_t)n * HH + kc + u]);
            } else {
#pragma unroll
                for (int u = 0; u < 8; ++u) o[u] = 0;
            }
        } else {
            int kk = kc - HH;
#pragma unroll
            for (int u = 0; u < 8; ++u) {
                int k2 = kk + u;
                ushort_t v = 0;
                if (k2 < EE) {
                    if (n < 2048) v = f2bf(W_ih_e[(size_t)n * EE + k2]);
                    else if (n >= G3) v = f2bf(W_ih_e[(size_t)(n - HH) * EE + k2]);
                }
                o[u] = v;
            }
        }
        *(int4*)(W_enc_big + (size_t)n * KE + kc) = *(int4*)o;
    } else {
        int nd = n - G4;
        if (kc < 128) {
#pragma unroll
            for (int u = 0; u < 8; ++u) {
                int k2 = kc + u;
                o[u] = (k2 < EE) ? f2bf(W_ih_d[(size_t)nd * 1124 + k2]) : (ushort_t)0;
            }
        } else {
#pragma unroll
            for (int u = 0; u < 8; ++u) o[u] = f2bf(W_ih_d[(size_t)nd * 1124 + EE + (kc - 128) + u]);
        }
        *(int4*)(W_dec_pad + (size_t)nd * KE + kc) = *(int4*)o;
    }
}

__global__ void conv_w(const float* __restrict__ W_hh_d, const float* __restrict__ W_fc,
                       ushort_t* __restrict__ W_hhd_b, ushort_t* __restrict__ W_fc_b) {
    int idx = blockIdx.x * 256 + threadIdx.x;
    const int N1 = G3 * HH / 8;
    const float* src;
    ushort_t* dst;
    size_t e;
    if (idx < N1) { e = (size_t)idx * 8; src = W_hh_d; dst = W_hhd_b; }
    else { e = (size_t)(idx - N1) * 8; src = W_fc; dst = W_fc_b; }
    float4 a = *(const float4*)(src + e);
    float4 b = *(const float4*)(src + e + 4);
    ushort_t o[8] = {f2bf(a.x), f2bf(a.y), f2bf(a.z), f2bf(a.w),
                     f2bf(b.x), f2bf(b.y), f2bf(b.z), f2bf(b.w)};
    *(int4*)(dst + e) = *(int4*)o;
}

// ---------------------------------------------------------------------------
// prep_x: emb_pad, A_enc0 = [h0 | emb_0], h_enc fp32, A_dec demb part, ce_sum=0
// ---------------------------------------------------------------------------
__global__ void prep_x(const int* __restrict__ inputs, const int* __restrict__ targets,
                       const float* __restrict__ h0, const float* __restrict__ E_enc,
                       const float* __restrict__ E_dec,
                       ushort_t* __restrict__ emb_pad, ushort_t* __restrict__ A_enc,
                       float* __restrict__ h_enc, ushort_t* __restrict__ A_dec,
                       float* __restrict__ ce_sum) {
    int idx = blockIdx.x * 256 + threadIdx.x;
    const int R0 = SS * BB * 128;
    const int R1 = R0 + BB * KE;
    const int R2 = R1 + BB * HH;
    const int R3 = R2 + (TT - 1) * BB * 128;
    const int R4 = R3 + 32;
    if (idx < R0) {
        int s = idx >> 15;
        int r = idx & 32767;
        int b = r >> 7, k = r & 127;
        emb_pad[idx] = (k < EE) ? f2bf(E_enc[(size_t)inputs[b * SS + s] * EE + k]) : (ushort_t)0;
    } else if (idx < R1) {
        int i = idx - R0;
        int b = i / KE, c = i - b * KE;
        ushort_t v;
        if (c < HH) v = f2bf(h0[b * HH + c]);
        else { int kk = c - HH; v = (kk < EE) ? f2bf(E_enc[(size_t)inputs[b * SS] * EE + kk]) : (ushort_t)0; }
        A_enc[i] = v;
    } else if (idx < R2) {
        int i = idx - R1;
        h_enc[i] = h0[i];
    } else if (idx < R3) {
        int i = idx - R2;
        int t = i >> 15;
        int r = i & 32767;
        int b = r >> 7, k = r & 127;
        int tok = (t == 0) ? 1 : targets[b * TT + t];
        A_dec[((size_t)(t * BB + b)) * KE + k] = (k < EE) ? f2bf(E_dec[(size_t)tok * EE + k]) : (ushort_t)0;
    } else if (idx < R4) {
        ce_sum[idx - R3] = 0.f;
    }
}

// ---------------------------------------------------------------------------
// Fused encoder step. NEW: ping-pong LDS A-tile + one lgkm-only barrier per
// 64-wide K-chunk (global loads span the barrier), and XOR-swizzled As
// (128B rows: slot ^= row&7) to kill the 16-way ds_read_b128 conflict.
// ---------------------------------------------------------------------------
__global__ __launch_bounds__(256) void enc_step(
    const ushort_t* __restrict__ Ain, ushort_t* __restrict__ Aout,
    const ushort_t* __restrict__ W, const float* __restrict__ bi,
    const float* __restrict__ bh, float* __restrict__ h,
    const ushort_t* __restrict__ emb_pad, const int* __restrict__ lengths,
    float* __restrict__ ctx_f, ushort_t* __restrict__ ctx_b, int s) {
    __shared__ ushort_t As[2][64 * 64];
    __shared__ float gbuf[4][64 * 33];
    int tid = threadIdx.x;
    int lane = tid & 63, g = tid >> 6;
    int j0 = blockIdx.x << 5, m0 = blockIdx.y << 6;
    int r16 = lane & 15, q = lane >> 4, q8 = q << 3;
    int srow = tid >> 3, skc = (tid & 7) << 3;
    const ushort_t* ap0 = Ain + (size_t)(m0 + srow) * KE + skc;
    const ushort_t* ap1 = ap0 + (size_t)32 * KE;
    const int sx = (srow & 7) << 3;                 // (srow+32)&7 == srow&7
    const int sw0 = (srow << 6) + (skc ^ sx);
    const int sw1 = ((srow + 32) << 6) + (skc ^ sx);
    const ushort_t* wb0 = W + (size_t)(g * 1024 + j0 + r16) * KE + q8;
    const ushort_t* wb1 = wb0 + (size_t)16 * KE;
    f32x4 zero = {0.f, 0.f, 0.f, 0.f};
    f32x4 acc[4][2];
#pragma unroll
    for (int i = 0; i < 4; ++i) { acc[i][0] = zero; acc[i][1] = zero; }
    // prologue: chunk0 -> LDS[0]; issue chunk1 A loads; W frags chunk0
    int4 va0 = *(const int4*)(ap0);
    int4 va1 = *(const int4*)(ap1);
    bf16x8 wf00 = *(const bf16x8*)(wb0);
    bf16x8 wf01 = *(const bf16x8*)(wb1);
    bf16x8 wf10 = *(const bf16x8*)(wb0 + 32);
    bf16x8 wf11 = *(const bf16x8*)(wb1 + 32);
    *(int4*)(As[0] + sw0) = va0;
    *(int4*)(As[0] + sw1) = va1;
    va0 = *(const int4*)(ap0 + 64);
    va1 = *(const int4*)(ap1 + 64);
    __syncthreads();
    int p = 0;
    for (int k0 = 0; k0 < KE; k0 += 64) {
        int kn = k0 + 64;
        bf16x8 wn00, wn01, wn10, wn11;
        if (kn < KE) {
            *(int4*)(As[p ^ 1] + sw0) = va0;      // stage chunk k0+64
            *(int4*)(As[p ^ 1] + sw1) = va1;
            if (kn + 64 < KE) {                   // issue chunk k0+128
                va0 = *(const int4*)(ap0 + kn + 64);
                va1 = *(const int4*)(ap1 + kn + 64);
            }
            wn00 = *(const bf16x8*)(wb0 + kn);    // W prefetch chunk k0+64
            wn01 = *(const bf16x8*)(wb1 + kn);
            wn10 = *(const bf16x8*)(wb0 + kn + 32);
            wn11 = *(const bf16x8*)(wb1 + kn + 32);
        }
        const ushort_t* Ab = As[p];
#pragma unroll
        for (int i = 0; i < 4; ++i) {
            int row = (i << 4) + r16;
            int xr = (row & 7) << 3;
            bf16x8 af0 = *(const bf16x8*)(Ab + (row << 6) + (q8 ^ xr));
            bf16x8 af1 = *(const bf16x8*)(Ab + (row << 6) + ((q8 + 32) ^ xr));
            acc[i][0] = MFMA16(af0, wf00, acc[i][0]);
            acc[i][1] = MFMA16(af0, wf01, acc[i][1]);
            acc[i][0] = MFMA16(af1, wf10, acc[i][0]);
            acc[i][1] = MFMA16(af1, wf11, acc[i][1]);
        }
        if (kn < KE) { wf00 = wn00; wf01 = wn01; wf10 = wn10; wf11 = wn11; }
        LGKM_BARRIER();
        p ^= 1;
    }
#pragma unroll
    for (int i = 0; i < 4; ++i)
#pragma unroll
        for (int j2 = 0; j2 < 2; ++j2)
#pragma unroll
            for (int r = 0; r < 4; ++r)
                gbuf[g][(i * 16 + q * 4 + r) * 33 + j2 * 16 + r16] = acc[i][j2][r];
    __syncthreads();
    int m = tid & 63, jc0 = (tid >> 6) << 3;
    int bgl = m0 + m, gj = j0 + jc0;
    int sel = (lengths[bgl] - 1 == s);
    const float* g0 = &gbuf[0][m * 33 + jc0];
    const float* g1 = &gbuf[1][m * 33 + jc0];
    const float* g2 = &gbuf[2][m * 33 + jc0];
    const float* g3 = &gbuf[3][m * 33 + jc0];
    ushort_t hb8[8];
#pragma unroll
    for (int u = 0; u < 8; ++u) {
        int jg = gj + u;
        float rr = sigm(g0[u] + bi[jg] + bh[jg]);
        float zz = sigm(g1[u] + bi[1024 + jg] + bh[1024 + jg]);
        float hn = g2[u] + bh[2048 + jg];
        float inn = g3[u] + bi[2048 + jg];
        float nn = tanhf(inn + rr * hn);
        size_t hi = (size_t)bgl * 1024 + jg;
        float hp = h[hi];
        float h2 = (1.f - zz) * nn + zz * hp;
        h[hi] = h2;
        hb8[u] = f2bf(h2);
        if (sel) { ctx_f[hi] = h2; ctx_b[hi] = hb8[u]; }
    }
    *(int4*)(Aout + (size_t)bgl * KE + gj) = *(int4*)hb8;
    if (blockIdx.x == 0 && s + 1 < SS) {
        int rr2 = tid >> 2, c0 = (tid & 3) << 5;
#pragma unroll
        for (int cc = 0; cc < 32; cc += 8) {
            int4 v = *(const int4*)(emb_pad + ((size_t)(s + 1) * BB + m0 + rr2) * 128 + c0 + cc);
            *(int4*)(Aout + (size_t)(m0 + rr2) * KE + 1024 + c0 + cc) = v;
        }
    }
}

// Fill A_dec ctx columns; init decoder h (fp32) + hb0 (bf16)
__global__ void fill_ctx(const float* __restrict__ ctx_f, const ushort_t* __restrict__ ctx_b,
                         ushort_t* __restrict__ A_dec, float* __restrict__ h_dec,
                         ushort_t* __restrict__ hb0) {
    int idx = blockIdx.x * 256 + threadIdx.x;  // 19*256*1024
    int t = idx >> 18;
    int r = idx & 262143;
    ushort_t v = ctx_b[r];
    int b = r >> 10;
    int k = r & 1023;
    A_dec[((size_t)(t * BB + b)) * KE + 128 + k] = v;
    if (t == 0) { h_dec[r] = ctx_f[r]; hb0[r] = v; }
}

// ---------------------------------------------------------------------------
// 128x128 MFMA GEMM, ping-pong LDS + lgkm-only barrier + XOR swizzle
// (64B rows: slot ^= (row>>1)&3).
// ---------------------------------------------------------------------------
template <typename OutT>
__global__ __launch_bounds__(256) void gemm128(const ushort_t* __restrict__ A,
                                               const ushort_t* __restrict__ W,
                                               OutT* __restrict__ C,
                                               int K, int lda, int ldw, int ldc) {
    __shared__ ushort_t As[2][128 * 32];
    __shared__ ushort_t Bs[2][128 * 32];
    int tid = threadIdx.x;
    int lane = tid & 63, wave = tid >> 6;
    int m0 = blockIdx.y << 7, n0 = blockIdx.x << 7;
    int row0 = tid >> 2, kc0 = (tid & 3) << 3;
    const ushort_t* a0p = A + (size_t)(m0 + row0) * lda + kc0;
    const ushort_t* a1p = A + (size_t)(m0 + row0 + 64) * lda + kc0;
    const ushort_t* w0p = W + (size_t)(n0 + row0) * ldw + kc0;
    const ushort_t* w1p = W + (size_t)(n0 + row0 + 64) * ldw + kc0;
    int mq = (wave >> 1) << 6, nq = (wave & 1) << 6;
    int r16 = lane & 15, q8 = (lane >> 4) << 3;
    const int sx = ((row0 >> 1) & 3) << 3;          // same bits for row0+64
    const int sw0 = (row0 << 5) + (kc0 ^ sx);
    const int sw1 = ((row0 + 64) << 5) + (kc0 ^ sx);
    f32x4 zero4 = {0.f, 0.f, 0.f, 0.f};
    f32x4 acc[4][4];
#pragma unroll
    for (int i = 0; i < 4; ++i)
#pragma unroll
        for (int j = 0; j < 4; ++j) acc[i][j] = zero4;
    int4 va0 = *(const int4*)(a0p);
    int4 va1 = *(const int4*)(a1p);
    int4 vb0 = *(const int4*)(w0p);
    int4 vb1 = *(const int4*)(w1p);
    *(int4*)(As[0] + sw0) = va0;
    *(int4*)(As[0] + sw1) = va1;
    *(int4*)(Bs[0] + sw0) = vb0;
    *(int4*)(Bs[0] + sw1) = vb1;
    va0 = *(const int4*)(a0p + 32);
    va1 = *(const int4*)(a1p + 32);
    vb0 = *(const int4*)(w0p + 32);
    vb1 = *(const int4*)(w1p + 32);
    __syncthreads();
    int p = 0;
    for (int k0 = 0; k0 < K; k0 += 32) {
        int kn = k0 + 32;
        if (kn < K) {
            *(int4*)(As[p ^ 1] + sw0) = va0;
            *(int4*)(As[p ^ 1] + sw1) = va1;
            *(int4*)(Bs[p ^ 1] + sw0) = vb0;
            *(int4*)(Bs[p ^ 1] + sw1) = vb1;
            if (kn + 32 < K) {
                va0 = *(const int4*)(a0p + kn + 32);
                va1 = *(const int4*)(a1p + kn + 32);
                vb0 = *(const int4*)(w0p + kn + 32);
                vb1 = *(const int4*)(w1p + kn + 32);
            }
        }
        bf16x8 af[4], bfv[4];
#pragma unroll
        for (int i = 0; i < 4; ++i) {
            int ar = mq + i * 16 + r16;
            af[i] = *(const bf16x8*)(As[p] + (ar << 5) + (q8 ^ ((((ar) >> 1) & 3) << 3)));
        }
#pragma unroll
        for (int j = 0; j < 4; ++j) {
            int br = nq + j * 16 + r16;
            bfv[j] = *(const bf16x8*)(Bs[p] + (br << 5) + (q8 ^ ((((br) >> 1) & 3) << 3)));
        }
#pragma unroll
        for (int i = 0; i < 4; ++i)
#pragma unroll
            for (int j = 0; j < 4; ++j) acc[i][j] = MFMA16(af[i], bfv[j], acc[i][j]);
        LGKM_BARRIER();
        p ^= 1;
    }
    int rbase = (lane >> 4) << 2;
#pragma unroll
    for (int i = 0; i < 4; ++i)
#pragma unroll
        for (int j = 0; j < 4; ++j)
#pragma unroll
            for (int r = 0; r < 4; ++r)
                storeC(&C[(size_t)(m0 + mq + i * 16 + rbase + r) * ldc + (n0 + nq + j * 16 + r16)],
                       acc[i][j][r]);
}

// ---------------------------------------------------------------------------
// Fused decoder recurrent step (3 gate groups) — same pipeline/swizzle as enc.
// ---------------------------------------------------------------------------
__global__ __launch_bounds__(256) void dec_step(
    const ushort_t* __restrict__ Ain, ushort_t* __restrict__ Aout,
    const ushort_t* __restrict__ W, const ushort_t* __restrict__ gi,
    const float* __restrict__ bi, const float* __restrict__ bh,
    float* __restrict__ h) {
    __shared__ ushort_t As[2][64 * 64];
    __shared__ float gbuf[3][64 * 33];
    int tid = threadIdx.x;
    int lane = tid & 63, g = tid >> 6;
    int j0 = blockIdx.x << 5, m0 = blockIdx.y << 6;
    int r16 = lane & 15, q = lane >> 4, q8 = q << 3;
    int srow = tid >> 3, skc = (tid & 7) << 3;
    const ushort_t* ap0 = Ain + (size_t)(m0 + srow) * HH + skc;
    const ushort_t* ap1 = ap0 + (size_t)32 * HH;
    const int sx = (srow & 7) << 3;
    const int sw0 = (srow << 6) + (skc ^ sx);
    const int sw1 = ((srow + 32) << 6) + (skc ^ sx);
    const ushort_t* wb0 = W + (size_t)(g * 1024 + j0 + r16) * HH + q8;
    const ushort_t* wb1 = wb0 + (size_t)16 * HH;
    f32x4 zero = {0.f, 0.f, 0.f, 0.f};
    f32x4 acc[4][2];
#pragma unroll
    for (int i = 0; i < 4; ++i) { acc[i][0] = zero; acc[i][1] = zero; }
    int4 va0 = *(const int4*)(ap0);
    int4 va1 = *(const int4*)(ap1);
    bf16x8 wf00 = {0, 0, 0, 0, 0, 0, 0, 0}, wf01 = wf00, wf10 = wf00, wf11 = wf00;
    if (g < 3) {
        wf00 = *(const bf16x8*)(wb0);
        wf01 = *(const bf16x8*)(wb1);
        wf10 = *(const bf16x8*)(wb0 + 32);
        wf11 = *(const bf16x8*)(wb1 + 32);
    }
    *(int4*)(As[0] + sw0) = va0;
    *(int4*)(As[0] + sw1) = va1;
    va0 = *(const int4*)(ap0 + 64);
    va1 = *(const int4*)(ap1 + 64);
    __syncthreads();
    int p = 0;
    for (int k0 = 0; k0 < HH; k0 += 64) {
        int kn = k0 + 64;
        bf16x8 wn00, wn01, wn10, wn11;
        if (kn < HH) {
            *(int4*)(As[p ^ 1] + sw0) = va0;
            *(int4*)(As[p ^ 1] + sw1) = va1;
            if (kn + 64 < HH) {
                va0 = *(const int4*)(ap0 + kn + 64);
                va1 = *(const int4*)(ap1 + kn + 64);
            }
            if (g < 3) {
                wn00 = *(const bf16x8*)(wb0 + kn);
                wn01 = *(const bf16x8*)(wb1 + kn);
                wn10 = *(const bf16x8*)(wb0 + kn + 32);
                wn11 = *(const bf16x8*)(wb1 + kn + 32);
            }
        }
        if (g < 3) {
            const ushort_t* Ab = As[p];
#pragma unroll
            for (int i = 0; i < 4; ++i) {
                int row = (i << 4) + r16;
                int xr = (row & 7) << 3;
                bf16x8 af0 = *(const bf16x8*)(Ab + (row << 6) + (q8 ^ xr));
                bf16x8 af1 = *(const bf16x8*)(Ab + (row << 6) + ((q8 + 32) ^ xr));
                acc[i][0] = MFMA16(af0, wf00, acc[i][0]);
                acc[i][1] = MFMA16(af0, wf01, acc[i][1]);
                acc[i][0] = MFMA16(af1, wf10, acc[i][0]);
                acc[i][1] = MFMA16(af1, wf11, acc[i][1]);
            }
            if (kn < HH) { wf00 = wn00; wf01 = wn01; wf10 = wn10; wf11 = wn11; }
        }
        LGKM_BARRIER();
        p ^= 1;
    }
    if (g < 3) {
#pragma unroll
        for (int i = 0; i < 4; ++i)
#pragma unroll
            for (int j2 = 0; j2 < 2; ++j2)
#pragma unroll
                for (int r = 0; r < 4; ++r)
                    gbuf[g][(i * 16 + q * 4 + r) * 33 + j2 * 16 + r16] = acc[i][j2][r];
    }
    __syncthreads();
    int m = tid & 63, jc0 = (tid >> 6) << 3;
    int bgl = m0 + m, gj = j0 + jc0;
    const ushort_t* gip = gi + (size_t)bgl * G3;
    ushort_t gr[8], gz[8], gn[8], hb8[8];
    *(int4*)gr = *(const int4*)(gip + gj);
    *(int4*)gz = *(const int4*)(gip + 1024 + gj);
    *(int4*)gn = *(const int4*)(gip + 2048 + gj);
    const float* g0 = &gbuf[0][m * 33 + jc0];
    const float* g1 = &gbuf[1][m * 33 + jc0];
    const float* g2 = &gbuf[2][m * 33 + jc0];
#pragma unroll
    for (int u = 0; u < 8; ++u) {
        int jg = gj + u;
        float rr = sigm(g0[u] + bh[jg] + bf2f(gr[u]) + bi[jg]);
        float zz = sigm(g1[u] + bh[1024 + jg] + bf2f(gz[u]) + bi[1024 + jg]);
        float hn = g2[u] + bh[2048 + jg];
        float inn = bf2f(gn[u]) + bi[2048 + jg];
        float nn = tanhf(inn + rr * hn);
        size_t hi = (size_t)bgl * 1024 + jg;
        float hp = h[hi];
        float h2 = (1.f - zz) * nn + zz * hp;
        h[hi] = h2;
        hb8[u] = f2bf(h2);
    }
    *(int4*)(Aout + (size_t)bgl * 1024 + gj) = *(int4*)hb8;
}

// ---------------------------------------------------------------------------
// BATCHED fused logits GEMM + CE partials over ALL 19 steps at once.
// A = H_all [19*256][1024]; grid (38 m-tiles, 250 n-tiles), m fastest so
// consecutive blocks share the same W_fc n-panel (L2 locality).
// row -> (t = row>>8, b = row&255).
// ---------------------------------------------------------------------------
__global__ __launch_bounds__(256) void logits_ce(
    const ushort_t* __restrict__ A, const ushort_t* __restrict__ Wf,
    const float* __restrict__ bfc, const int* __restrict__ targets,
    float* __restrict__ part_max, float* __restrict__ part_sum,
    float* __restrict__ xt) {
    __shared__ ushort_t As[2][128 * 32];
    __shared__ ushort_t Bs[2][128 * 32];
    __shared__ float wm[128][2], ws2[128][2];
    int tid = threadIdx.x;
    int lane = tid & 63, wave = tid >> 6;
    int m0 = blockIdx.x << 7, n0 = blockIdx.y << 7;
    int row0 = tid >> 2, kc0 = (tid & 3) << 3;
    const ushort_t* a0p = A + (size_t)(m0 + row0) * HH + kc0;
    const ushort_t* a1p = A + (size_t)(m0 + row0 + 64) * HH + kc0;
    const ushort_t* w0p = Wf + (size_t)(n0 + row0) * HH + kc0;
    const ushort_t* w1p = Wf + (size_t)(n0 + row0 + 64) * HH + kc0;
    int mq = (wave >> 1) << 6, nq = (wave & 1) << 6;
    int r16 = lane & 15, q = lane >> 4, q8 = q << 3;
    const int sx = ((row0 >> 1) & 3) << 3;
    const int sw0 = (row0 << 5) + (kc0 ^ sx);
    const int sw1 = ((row0 + 64) << 5) + (kc0 ^ sx);
    f32x4 zero4 = {0.f, 0.f, 0.f, 0.f};
    f32x4 acc[4][4];
#pragma unroll
    for (int i = 0; i < 4; ++i)
#pragma unroll
        for (int j = 0; j < 4; ++j) acc[i][j] = zero4;
    int4 va0 = *(const int4*)(a0p);
    int4 va1 = *(const int4*)(a1p);
    int4 vb0 = *(const int4*)(w0p);
    int4 vb1 = *(const int4*)(w1p);
    *(int4*)(As[0] + sw0) = va0;
    *(int4*)(As[0] + sw1) = va1;
    *(int4*)(Bs[0] + sw0) = vb0;
    *(int4*)(Bs[0] + sw1) = vb1;
    va0 = *(const int4*)(a0p + 32);
    va1 = *(const int4*)(a1p + 32);
    vb0 = *(const int4*)(w0p + 32);
    vb1 = *(const int4*)(w1p + 32);
    __syncthreads();
    int p = 0;
    for (int k0 = 0; k0 < HH; k0 += 32) {
        int kn = k0 + 32;
        if (kn < HH) {
            *(int4*)(As[p ^ 1] + sw0) = va0;
            *(int4*)(As[p ^ 1] + sw1) = va1;
            *(int4*)(Bs[p ^ 1] + sw0) = vb0;
            *(int4*)(Bs[p ^ 1] + sw1) = vb1;
            if (kn + 32 < HH) {
                va0 = *(const int4*)(a0p + kn + 32);
                va1 = *(const int4*)(a1p + kn + 32);
                vb0 = *(const int4*)(w0p + kn + 32);
                vb1 = *(const int4*)(w1p + kn + 32);
            }
        }
        bf16x8 af[4], bfv[4];
#pragma unroll
        for (int i = 0; i < 4; ++i) {
            int ar = mq + i * 16 + r16;
            af[i] = *(const bf16x8*)(As[p] + (ar << 5) + (q8 ^ ((((ar) >> 1) & 3) << 3)));
        }
#pragma unroll
        for (int j = 0; j < 4; ++j) {
            int br = nq + j * 16 + r16;
            bfv[j] = *(const bf16x8*)(Bs[p] + (br << 5) + (q8 ^ ((((br) >> 1) & 3) << 3)));
        }
#pragma unroll
        for (int i = 0; i < 4; ++i)
#pragma unroll
            for (int j = 0; j < 4; ++j) acc[i][j] = MFMA16(af[i], bfv[j], acc[i][j]);
        LGKM_BARRIER();
        p ^= 1;
    }
    float bias[4];
#pragma unroll
    for (int j2 = 0; j2 < 4; ++j2) bias[j2] = bfc[n0 + nq + j2 * 16 + r16];
    int nw = wave & 1;
#pragma unroll
    for (int i = 0; i < 4; ++i) {
#pragma unroll
        for (int r = 0; r < 4; ++r) {
            int rloc = mq + i * 16 + q * 4 + r;
            int brow = m0 + rloc;
            int y = targets[(brow & 255) * TT + (brow >> 8) + 1];
            float v[4];
            float mx = -3.0e38f;
#pragma unroll
            for (int j2 = 0; j2 < 4; ++j2) {
                v[j2] = acc[i][j2][r] + bias[j2];
                if (n0 + nq + j2 * 16 + r16 == y) xt[brow] = v[j2];
                mx = fmaxf(mx, v[j2]);
            }
#pragma unroll
            for (int d = 1; d < 16; d <<= 1) mx = fmaxf(mx, __shfl_xor(mx, d, 64));
            float se = 0.f;
#pragma unroll
            for (int j2 = 0; j2 < 4; ++j2) se += expf(v[j2] - mx);
#pragma unroll
            for (int d = 1; d < 16; d <<= 1) se += __shfl_xor(se, d, 64);
            if (r16 == 0) { wm[rloc][nw] = mx; ws2[rloc][nw] = se; }
        }
    }
    __syncthreads();
    if (tid < 128) {
        float m0v = wm[tid][0], m1v = wm[tid][1];
        float M = fmaxf(m0v, m1v);
        float S = ws2[tid][0] * expf(m0v - M) + ws2[tid][1] * expf(m1v - M);
        int brow = m0 + tid;
        part_max[(size_t)brow * 256 + blockIdx.y] = M;
        part_sum[(size_t)brow * 256 + blockIdx.y] = S;
    }
}

// Merge 250 per-row partials -> CE for all 4864 rows; atomicAdd ce_sum[t]
__global__ void ce_merge(const float* __restrict__ pm, const float* __restrict__ ps,
                         const float* __restrict__ xt, float* __restrict__ ce_sum) {
    int row = blockIdx.x * 4 + (threadIdx.x >> 6);
    int lane = threadIdx.x & 63;
    const float* pmr = pm + (size_t)row * 256;
    const float* psr = ps + (size_t)row * 256;
    float lm[4];
    int cnt = 0;
    float mx = -3.0e38f;
    for (int i = lane; i < 250; i += 64) { float v = pmr[i]; lm[cnt++] = v; mx = fmaxf(mx, v); }
    for (int d = 1; d < 64; d <<= 1) mx = fmaxf(mx, __shfl_xor(mx, d, 64));
    float s = 0.f;
    cnt = 0;
    for (int i = lane; i < 250; i += 64) { s += psr[i] * expf(lm[cnt++] - mx); }
    for (int d = 1; d < 64; d <<= 1) s += __shfl_xor(s, d, 64);
    if (lane == 0) atomicAdd(&ce_sum[row >> 8], mx + logf(s) - xt[row]);
}

// loss = (1/T) * sum_t (ce_sum[t]/B) * (mask_sum[t]/B)
__global__ void finalize(const float* __restrict__ ce_sum, const int* __restrict__ targets,
                         float* __restrict__ out) {
    int lane = threadIdx.x;
    float term = 0.f;
    if (lane < TT - 1) {
        int msum = 0;
        for (int b = 0; b < BB; ++b) msum += (targets[b * TT + lane + 1] >= 1) ? 1 : 0;
        term = (ce_sum[lane] * (1.f / BB)) * ((float)msum * (1.f / BB));
    }
    for (int off = 32; off > 0; off >>= 1) term += __shfl_down(term, off, 64);
    if (lane == 0) out[0] = term * (1.f / TT);
}

extern "C" void kernel_launch(void* const* d_in, const int* in_sizes, int n_in,
                              void* d_out, int out_size, void* d_ws, size_t ws_size,
                              hipStream_t stream) {
    const int* inputs = (const int*)d_in[0];
    const int* targets = (const int*)d_in[1];
    const int* lengths = (const int*)d_in[2];
    const float* h0 = (const float*)d_in[3];
    const float* E_enc = (const float*)d_in[4];
    const float* E_dec = (const float*)d_in[5];
    const float* W_ih_e = (const float*)d_in[6];
    const float* W_hh_e = (const float*)d_in[7];
    const float* b_ih_e = (const float*)d_in[8];
    const float* b_hh_e = (const float*)d_in[9];
    const float* W_ih_d = (const float*)d_in[10];
    const float* W_hh_d = (const float*)d_in[11];
    const float* b_ih_d = (const float*)d_in[12];
    const float* b_hh_d = (const float*)d_in[13];
    const float* W_fc = (const float*)d_in[14];
    const float* b_fc = (const float*)d_in[15];

    char* ws = (char*)d_ws;
    size_t off = 0;
    auto alloc = [&](size_t bytes) -> char* {
        char* p = ws + off;
        off += (bytes + 255) & ~(size_t)255;
        return p;
    };
    const int MROWS = (TT - 1) * BB;  // 4864
    ushort_t* W_enc_big = (ushort_t*)alloc((size_t)G4 * KE * 2);
    ushort_t* W_dec_pad = (ushort_t*)alloc((size_t)G3 * KE * 2);
    ushort_t* W_hhd_b = (ushort_t*)alloc((size_t)G3 * HH * 2);
    ushort_t* W_fc_b = (ushort_t*)alloc((size_t)VV * HH * 2);
    ushort_t* emb_pad = (ushort_t*)alloc((size_t)SS * BB * 128 * 2);
    ushort_t* A_enc0 = (ushort_t*)alloc((size_t)BB * KE * 2);
    ushort_t* A_enc1 = (ushort_t*)alloc((size_t)BB * KE * 2);
    ushort_t* A_dec = (ushort_t*)alloc((size_t)MROWS * KE * 2);
    ushort_t* gi_dec = (ushort_t*)alloc((size_t)MROWS * G3 * 2);
    ushort_t* H_all = (ushort_t*)alloc((size_t)MROWS * HH * 2);
    float* h_enc = (float*)alloc((size_t)BB * HH * 4);
    float* ctx_f = (float*)alloc((size_t)BB * HH * 4);
    ushort_t* ctx_b = (ushort_t*)alloc((size_t)BB * HH * 2);
    float* h_dec = (float*)alloc((size_t)BB * HH * 4);
    ushort_t* hb0 = (ushort_t*)alloc((size_t)BB * HH * 2);
    float* part_max = (float*)alloc((size_t)MROWS * 256 * 4);
    float* part_sum = (float*)alloc((size_t)MROWS * 256 * 4);
    float* xt = (float*)alloc((size_t)MROWS * 4);
    float* ce_sum = (float*)alloc(64 * 4);
    ushort_t* Aenc[2] = {A_enc0, A_enc1};

    // ---- prep ----
    prep_w<<<(G4 + G3) * (KE / 8) / 256, 256, 0, stream>>>(W_hh_e, W_ih_e, W_ih_d,
                                                           W_enc_big, W_dec_pad);
    conv_w<<<(G3 * HH + VV * HH) / 8 / 256, 256, 0, stream>>>(W_hh_d, W_fc, W_hhd_b, W_fc_b);
    {
        int nx = SS * BB * 128 + BB * KE + BB * HH + (TT - 1) * BB * 128 + 32;
        prep_x<<<(nx + 255) / 256, 256, 0, stream>>>(inputs, targets, h0, E_enc, E_dec,
                                                     emb_pad, A_enc0, h_enc, A_dec, ce_sum);
    }

    // ---- encoder: 64 fused steps (double-buffered A) ----
    for (int s = 0; s < SS; ++s)
        enc_step<<<dim3(32, 4), 256, 0, stream>>>(Aenc[s & 1], Aenc[(s + 1) & 1], W_enc_big,
                                                  b_ih_e, b_hh_e, h_enc, emb_pad, lengths,
                                                  ctx_f, ctx_b, s);

    // ---- decoder input-side gates: one big GEMM ----
    fill_ctx<<<((TT - 1) * BB * HH) / 256, 256, 0, stream>>>(ctx_f, ctx_b, A_dec, h_dec, hb0);
    gemm128<ushort_t><<<dim3(G3 / 128, MROWS / 128), 256, 0, stream>>>(
        A_dec, W_dec_pad, gi_dec, KE, KE, KE, G3);

    // ---- decoder: 19 fused recurrent steps writing H_all ----
    for (int t = 0; t < TT - 1; ++t) {
        const ushort_t* hin = (t == 0) ? hb0 : (H_all + (size_t)(t - 1) * BB * HH);
        dec_step<<<dim3(32, 4), 256, 0, stream>>>(hin, H_all + (size_t)t * BB * HH, W_hhd_b,
                                                  gi_dec + (size_t)t * BB * G3,
                                                  b_ih_d, b_hh_d, h_dec);
    }

    // ---- ONE batched logits+CE over all 19 steps, then one merge ----
    logits_ce<<<dim3(MROWS / 128, VV / 128), 256, 0, stream>>>(H_all, W_fc_b, b_fc, targets,
                                                               part_max, part_sum, xt);
    ce_merge<<<MROWS / 4, 256, 0, stream>>>(part_max, part_sum, xt, ce_sum);

    finalize<<<1, 64, 0, stream>>>(ce_sum, targets, (float*)d_out);
}